// Round 2
// 709.471 us; speedup vs baseline: 1.1099x; 1.1099x over previous
//
#include <hip/hip_runtime.h>

typedef __attribute__((ext_vector_type(8))) short short8;
typedef __attribute__((ext_vector_type(8))) unsigned short ushort8;
typedef __attribute__((ext_vector_type(4))) float floatx4;

#define T_TOK 1024
#define H_DIM 2048
#define I_DIM 768
#define E_NUM 32
#define TOPK  8

// ---- workspace layout (bytes) ----
#define OFF_CNT   0                      // 32 * 4
#define OFF_OFFS  512                    // 33 * 4
#define OFF_LIST  1024                   // 32*1024*4
#define OFF_TIDX  132096                 // 1024*8*4
#define OFF_TPOS  164864                 // 1024*8*4
#define OFF_TW    197632                 // 1024*8*4
#define OFF_ACT   262144                 // 8192*768*2  = 12,582,912 (bf16)
#define OFF_XG    12845056               // 8192*2048*2 = 33,554,432 (bf16)
#define OFF_Y     OFF_XG                 // y aliases Xg (Xg dead after gemm_gu)

__device__ __forceinline__ unsigned short f2bf(float f) {
  unsigned int u = __builtin_bit_cast(unsigned int, f);
  u += 0x7fffu + ((u >> 16) & 1u);           // RNE
  return (unsigned short)(u >> 16);
}
__device__ __forceinline__ float bf2f(unsigned short h) {
  unsigned int u = ((unsigned int)h) << 16;
  return __builtin_bit_cast(float, u);
}
__device__ __forceinline__ void async_copy16(const void* g, void* l) {
  __builtin_amdgcn_global_load_lds(
      (const __attribute__((address_space(1))) unsigned int*)g,
      (__attribute__((address_space(3))) unsigned int*)l, 16, 0, 0);
}
__device__ __forceinline__ void cvt16(const floatx4& a, const floatx4& b,
                                      const floatx4& c, const floatx4& d,
                                      ushort8& p0, ushort8& p1) {
#pragma unroll
  for (int z = 0; z < 4; z++) {
    p0[z] = f2bf(a[z]); p0[z + 4] = f2bf(b[z]);
    p1[z] = f2bf(c[z]); p1[z + 4] = f2bf(d[z]);
  }
}

// ---------------- router: logits (fp32, exact) + softmax + top8 + assignment ----------------
__global__ __launch_bounds__(256) void router_kernel(
    const float* __restrict__ x, const float* __restrict__ gw,
    float* __restrict__ logits_out, int* __restrict__ cnt, int* __restrict__ list,
    int* __restrict__ tidx, int* __restrict__ tpos, float* __restrict__ tw)
{
  int t = blockIdx.x;
  int tid = threadIdx.x;
  int wave = tid >> 6, lane = tid & 63;
  const float* xr = x + (size_t)t * H_DIM;
  float xv[32];
#pragma unroll
  for (int i = 0; i < 32; i++) xv[i] = xr[lane + 64 * i];

  __shared__ float lg[E_NUM];
  for (int ee = 0; ee < 8; ee++) {
    int e = wave * 8 + ee;
    const float* wr = gw + (size_t)e * H_DIM;
    float acc = 0.f;
#pragma unroll
    for (int i = 0; i < 32; i++) acc += xv[i] * wr[lane + 64 * i];
    for (int m = 32; m >= 1; m >>= 1) acc += __shfl_xor(acc, m, 64);
    if (lane == 0) lg[e] = acc;
  }
  __syncthreads();

  if (tid < E_NUM) logits_out[t * E_NUM + tid] = lg[tid];

  if (wave == 0) {
    float logit = (lane < E_NUM) ? lg[lane] : -1e30f;
    float mx = logit;
    for (int m = 16; m >= 1; m >>= 1) mx = fmaxf(mx, __shfl_xor(mx, m, 64));
    float p = (lane < E_NUM) ? expf(logit - mx) : 0.f;
    float sum = p;
    for (int m = 16; m >= 1; m >>= 1) sum += __shfl_xor(sum, m, 64);
    p /= sum;

    float rem = (lane < E_NUM) ? p : -1.f;
    int   seli[TOPK];
    float selw[TOPK];
    float sumw = 0.f;
#pragma unroll
    for (int k = 0; k < TOPK; k++) {
      float v = rem; int i = lane;
      for (int m = 16; m >= 1; m >>= 1) {
        float ov = __shfl_xor(v, m, 64);
        int   oi = __shfl_xor(i, m, 64);
        if (ov > v || (ov == v && oi < i)) { v = ov; i = oi; }
      }
      seli[k] = i; selw[k] = v; sumw += v;
      if (lane == i) rem = -1.f;
    }
    if (lane < TOPK) {
      int e = seli[lane];
      float w = selw[lane] / sumw;
      int pos = atomicAdd(&cnt[e], 1);
      list[e * 1024 + pos] = t;
      tidx[t * TOPK + lane] = e;
      tpos[t * TOPK + lane] = pos;
      tw[t * TOPK + lane] = w;
    }
  }
}

// ---------------- exclusive scan of expert counts ----------------
__global__ void scan_kernel(const int* __restrict__ cnt, int* __restrict__ offs) {
  if (threadIdx.x == 0) {
    int s = 0;
    for (int e = 0; e < E_NUM; e++) { offs[e] = s; s += cnt[e]; }
    offs[E_NUM] = s;
  }
}

// ---------------- gather + convert: Xg[slot][k] = bf16(x[token][k]) ----------------
__global__ __launch_bounds__(256) void gather_x(
    const float* __restrict__ x, const int* __restrict__ tidx,
    const int* __restrict__ tpos, const int* __restrict__ offs,
    unsigned short* __restrict__ xg)
{
  int t = blockIdx.x;
  int tid = threadIdx.x;
  const float* xr = x + (size_t)t * H_DIM + tid * 8;
  floatx4 a = *(const floatx4*)xr;
  floatx4 b = *(const floatx4*)(xr + 4);
  ushort8 p;
#pragma unroll
  for (int j = 0; j < 4; j++) { p[j] = f2bf(a[j]); p[j + 4] = f2bf(b[j]); }
#pragma unroll
  for (int k = 0; k < TOPK; k++) {
    int e = tidx[t * TOPK + k];
    int slot = offs[e] + tpos[t * TOPK + k];
    *(ushort8*)(xg + (size_t)slot * H_DIM + tid * 8) = p;
  }
}

// ---------------- gemm_gu: act = silu(Xg*Wg^T) * (Xg*Wu^T), fused ----------------
// Tile: M=256 (2 m-tiles/expert, 2nd exits when c<=256), N=128 (64 gate + 64 up cols).
// 4 waves, wave w owns rows [w*64, w*64+64): 4 m-frags x 8 n-frags.
// Double-buffered LDS, 2-phase pipeline: stage(t+1) issued before compute(t),
// W convert+ds_write after MFMA (issue-early / write-late), ONE barrier per K-step.
#define GU_NT 12
__global__ __launch_bounds__(256, 2) void gemm_gu(
    const unsigned short* __restrict__ xg,
    const float* __restrict__ gpw, const float* __restrict__ upw,
    const int* __restrict__ cnt, const int* __restrict__ offs,
    unsigned short* __restrict__ act)
{
  int bid = blockIdx.x;
  int e = bid & 31;                 // expert -> XCD pinning heuristic
  int rest = bid >> 5;              // 0..23
  int nt = rest % GU_NT;            // 0..11
  int mt = rest / GU_NT;            // 0..1
  int c = cnt[e];
  int m0 = mt * 256;
  if (m0 >= c) return;
  int crem = c - m0;
  int base = offs[e] + m0;
  int n0 = nt * 64;

  __shared__ __align__(16) unsigned char  As[2][256 * 64];   // 2 x 16 KB
  __shared__ __align__(16) unsigned short Ws[2][128 * 40];   // 2 x 10 KB

  int tid = threadIdx.x;
  int w = tid >> 6, lane = tid & 63;
  int q = lane >> 4, l15 = lane & 15;

  // W staging: thread covers W-row wr (0..63 gate, 64..127 up), 16-float half wc
  int wr = tid >> 1, wc = tid & 1;
  const float* wp = (wr < 64 ? gpw + ((size_t)e * I_DIM + n0 + wr) * H_DIM
                             : upw + ((size_t)e * I_DIM + n0 + (wr - 64)) * H_DIM) + wc * 16;
  int wofs = wr * 40 + wc * 16;

  // A staging: per wave 4 async insts, 16 rows each; XOR col swizzle for banks
  const unsigned short* agp[4];
  int aofs[4];
  {
    int rl = lane >> 2;
    int ch = (lane & 3) ^ ((lane >> 3) & 3);
#pragma unroll
    for (int g = 0; g < 4; g++) {
      int rm = w * 64 + g * 16 + rl;
      int slot = base + rm; if (slot > 8191) slot = 8191;
      agp[g] = xg + (size_t)slot * H_DIM + ch * 8;
      aofs[g] = (w * 64 + g * 16) * 64;
    }
  }
  // A frag read offsets
  int afo[4];
#pragma unroll
  for (int i = 0; i < 4; i++) {
    int row = w * 64 + i * 16 + l15;
    int chunk = q ^ ((row >> 1) & 3);
    afo[i] = row * 64 + chunk * 16;
  }
  int bfo[8];
#pragma unroll
  for (int j = 0; j < 8; j++) bfo[j] = (j * 16 + l15) * 40 + q * 8;

  int rem = crem - w * 64;
  int ni = rem <= 0 ? 0 : (rem >= 64 ? 4 : ((rem + 15) >> 4));
  bool wact = ni > 0;

  floatx4 acc[4][8];
#pragma unroll
  for (int i = 0; i < 4; i++)
#pragma unroll
    for (int j = 0; j < 8; j++) acc[i][j] = (floatx4){0.f, 0.f, 0.f, 0.f};

  floatx4 wv[4];
  // ---- prologue: stage k-tile 0 into buf 0 ----
  if (wact) {
#pragma unroll
    for (int g = 0; g < 4; g++) { async_copy16(agp[g], As[0] + aofs[g]); agp[g] += 32; }
  }
#pragma unroll
  for (int z = 0; z < 4; z++) wv[z] = *(const floatx4*)(wp + 4 * z);
  wp += 32;
  {
    ushort8 p0, p1; cvt16(wv[0], wv[1], wv[2], wv[3], p0, p1);
    *(ushort8*)&Ws[0][wofs] = p0;
    *(ushort8*)&Ws[0][wofs + 8] = p1;
  }
  __syncthreads();

  int buf = 0;
  for (int kt = 0; kt < H_DIM / 32; kt++) {
    bool notlast = (kt + 1 < H_DIM / 32);
    if (notlast) {
      if (wact) {
#pragma unroll
        for (int g = 0; g < 4; g++) { async_copy16(agp[g], As[buf ^ 1] + aofs[g]); agp[g] += 32; }
      }
#pragma unroll
      for (int z = 0; z < 4; z++) wv[z] = *(const floatx4*)(wp + 4 * z);
      wp += 32;
    }
    short8 bfr[8];
#pragma unroll
    for (int j = 0; j < 8; j++) bfr[j] = *(const short8*)&Ws[buf][bfo[j]];
#pragma unroll
    for (int i = 0; i < 4; i++) {
      if (i < ni) {
        short8 af = *(const short8*)(As[buf] + afo[i]);
#pragma unroll
        for (int j = 0; j < 8; j++)
          acc[i][j] = __builtin_amdgcn_mfma_f32_16x16x32_bf16(af, bfr[j], acc[i][j], 0, 0, 0);
      }
    }
    if (notlast) {
      ushort8 p0, p1; cvt16(wv[0], wv[1], wv[2], wv[3], p0, p1);
      *(ushort8*)&Ws[buf ^ 1][wofs] = p0;
      *(ushort8*)&Ws[buf ^ 1][wofs + 8] = p1;
      __syncthreads();
    }
    buf ^= 1;
  }

  // fused SiLU epilogue: act[slot][n0 + j*16 + l15] = silu(g)*u
#pragma unroll
  for (int i = 0; i < 4; i++) {
    if (i < ni) {
#pragma unroll
      for (int r = 0; r < 4; r++) {
        int s = w * 64 + i * 16 + q * 4 + r;
        if (s < crem) {
          size_t rowb = (size_t)(base + s) * I_DIM + n0;
#pragma unroll
          for (int j = 0; j < 4; j++) {
            float g = acc[i][j][r];
            float u = acc[i][j + 4][r];
            float sv = g / (1.f + __expf(-g));
            act[rowb + j * 16 + l15] = f2bf(sv * u);
          }
        }
      }
    }
  }
}

// ---------------- gemm_down: y = act * Wd^T ----------------
// Tile: M=256 x N=128 H-cols, same 2-phase double-buffered pipeline, K=768.
#define GD_NT 16
__global__ __launch_bounds__(256, 2) void gemm_down(
    const unsigned short* __restrict__ act,
    const float* __restrict__ dpw,
    const int* __restrict__ cnt, const int* __restrict__ offs,
    unsigned short* __restrict__ y)
{
  int bid = blockIdx.x;
  int e = bid & 31;
  int rest = bid >> 5;              // 0..31
  int nt = rest % GD_NT;            // 0..15
  int mt = rest / GD_NT;            // 0..1
  int c = cnt[e];
  int m0 = mt * 256;
  if (m0 >= c) return;
  int crem = c - m0;
  int base = offs[e] + m0;
  int h0 = nt * 128;

  __shared__ __align__(16) unsigned char  As[2][256 * 64];
  __shared__ __align__(16) unsigned short Ws[2][128 * 40];

  int tid = threadIdx.x;
  int w = tid >> 6, lane = tid & 63;
  int q = lane >> 4, l15 = lane & 15;

  int wr = tid >> 1, wc = tid & 1;
  const float* wp = dpw + ((size_t)e * H_DIM + h0 + wr) * I_DIM + wc * 16;
  int wofs = wr * 40 + wc * 16;

  const unsigned short* agp[4];
  int aofs[4];
  {
    int rl = lane >> 2;
    int ch = (lane & 3) ^ ((lane >> 3) & 3);
#pragma unroll
    for (int g = 0; g < 4; g++) {
      int rm = w * 64 + g * 16 + rl;
      int slot = base + rm; if (slot > 8191) slot = 8191;
      agp[g] = act + (size_t)slot * I_DIM + ch * 8;
      aofs[g] = (w * 64 + g * 16) * 64;
    }
  }
  int afo[4];
#pragma unroll
  for (int i = 0; i < 4; i++) {
    int row = w * 64 + i * 16 + l15;
    int chunk = q ^ ((row >> 1) & 3);
    afo[i] = row * 64 + chunk * 16;
  }
  int bfo[8];
#pragma unroll
  for (int j = 0; j < 8; j++) bfo[j] = (j * 16 + l15) * 40 + q * 8;

  int rem = crem - w * 64;
  int ni = rem <= 0 ? 0 : (rem >= 64 ? 4 : ((rem + 15) >> 4));
  bool wact = ni > 0;

  floatx4 acc[4][8];
#pragma unroll
  for (int i = 0; i < 4; i++)
#pragma unroll
    for (int j = 0; j < 8; j++) acc[i][j] = (floatx4){0.f, 0.f, 0.f, 0.f};

  floatx4 wv[4];
  if (wact) {
#pragma unroll
    for (int g = 0; g < 4; g++) { async_copy16(agp[g], As[0] + aofs[g]); agp[g] += 32; }
  }
#pragma unroll
  for (int z = 0; z < 4; z++) wv[z] = *(const floatx4*)(wp + 4 * z);
  wp += 32;
  {
    ushort8 p0, p1; cvt16(wv[0], wv[1], wv[2], wv[3], p0, p1);
    *(ushort8*)&Ws[0][wofs] = p0;
    *(ushort8*)&Ws[0][wofs + 8] = p1;
  }
  __syncthreads();

  int buf = 0;
  for (int kt = 0; kt < I_DIM / 32; kt++) {
    bool notlast = (kt + 1 < I_DIM / 32);
    if (notlast) {
      if (wact) {
#pragma unroll
        for (int g = 0; g < 4; g++) { async_copy16(agp[g], As[buf ^ 1] + aofs[g]); agp[g] += 32; }
      }
#pragma unroll
      for (int z = 0; z < 4; z++) wv[z] = *(const floatx4*)(wp + 4 * z);
      wp += 32;
    }
    short8 bfr[8];
#pragma unroll
    for (int j = 0; j < 8; j++) bfr[j] = *(const short8*)&Ws[buf][bfo[j]];
#pragma unroll
    for (int i = 0; i < 4; i++) {
      if (i < ni) {
        short8 af = *(const short8*)(As[buf] + afo[i]);
#pragma unroll
        for (int j = 0; j < 8; j++)
          acc[i][j] = __builtin_amdgcn_mfma_f32_16x16x32_bf16(af, bfr[j], acc[i][j], 0, 0, 0);
      }
    }
    if (notlast) {
      ushort8 p0, p1; cvt16(wv[0], wv[1], wv[2], wv[3], p0, p1);
      *(ushort8*)&Ws[buf ^ 1][wofs] = p0;
      *(ushort8*)&Ws[buf ^ 1][wofs + 8] = p1;
      __syncthreads();
    }
    buf ^= 1;
  }

#pragma unroll
  for (int i = 0; i < 4; i++) {
    if (i < ni) {
#pragma unroll
      for (int r = 0; r < 4; r++) {
        int s = w * 64 + i * 16 + q * 4 + r;
        if (s < crem) {
          size_t rowb = (size_t)(base + s) * H_DIM + h0;
#pragma unroll
          for (int j = 0; j < 8; j++)
            y[rowb + j * 16 + l15] = f2bf(acc[i][j][r]);
        }
      }
    }
  }
}

// ---------------- combine: out[t,h] = sum_k w * y[slot_k, h] ----------------
__global__ __launch_bounds__(256) void combine_kernel(
    const unsigned short* __restrict__ y,
    const int* __restrict__ tidx, const int* __restrict__ tpos,
    const float* __restrict__ tw, const int* __restrict__ offs,
    float* __restrict__ out)
{
  int t = blockIdx.x;
  int tid = threadIdx.x;
  int h = tid * 8;
  float acc[8];
#pragma unroll
  for (int j = 0; j < 8; j++) acc[j] = 0.f;
#pragma unroll
  for (int k = 0; k < TOPK; k++) {
    int e = tidx[t * TOPK + k];
    int p = tpos[t * TOPK + k];
    float w = tw[t * TOPK + k];
    size_t sg = (size_t)offs[e] + p;
    ushort8 v = *(const ushort8*)(y + sg * H_DIM + h);
#pragma unroll
    for (int j = 0; j < 8; j++) acc[j] += w * bf2f(v[j]);
  }
  floatx4 o0 = {acc[0], acc[1], acc[2], acc[3]};
  floatx4 o1 = {acc[4], acc[5], acc[6], acc[7]};
  *(floatx4*)(out + (size_t)t * H_DIM + h) = o0;
  *(floatx4*)(out + (size_t)t * H_DIM + h + 4) = o1;
}

extern "C" void kernel_launch(void* const* d_in, const int* in_sizes, int n_in,
                              void* d_out, int out_size, void* d_ws, size_t ws_size,
                              hipStream_t stream) {
  const float* x   = (const float*)d_in[0];
  const float* gw  = (const float*)d_in[1];
  const float* gpw = (const float*)d_in[2];
  const float* upw = (const float*)d_in[3];
  const float* dpw = (const float*)d_in[4];
  float* out = (float*)d_out;
  float* logits_out = out + (size_t)T_TOK * H_DIM;

  char* ws = (char*)d_ws;
  int*   cnt  = (int*)(ws + OFF_CNT);
  int*   offs = (int*)(ws + OFF_OFFS);
  int*   list = (int*)(ws + OFF_LIST);
  int*   tidx = (int*)(ws + OFF_TIDX);
  int*   tpos = (int*)(ws + OFF_TPOS);
  float* tw   = (float*)(ws + OFF_TW);
  unsigned short* act = (unsigned short*)(ws + OFF_ACT);
  unsigned short* xg  = (unsigned short*)(ws + OFF_XG);
  unsigned short* y   = (unsigned short*)(ws + OFF_Y);   // aliases xg

  hipMemsetAsync(cnt, 0, 128, stream);
  router_kernel<<<T_TOK, 256, 0, stream>>>(x, gw, logits_out, cnt, list, tidx, tpos, tw);
  scan_kernel<<<1, 64, 0, stream>>>(cnt, offs);
  gather_x<<<T_TOK, 256, 0, stream>>>(x, tidx, tpos, offs, xg);
  gemm_gu<<<GU_NT * 2 * E_NUM, 256, 0, stream>>>(xg, gpw, upw, cnt, offs, act);
  gemm_down<<<GD_NT * 2 * E_NUM, 256, 0, stream>>>(act, dpw, cnt, offs, y);
  combine_kernel<<<T_TOK, 256, 0, stream>>>(y, tidx, tpos, tw, offs, out);
}